// Round 1
// 96.054 us; speedup vs baseline: 1.0059x; 1.0059x over previous
//
#include <hip/hip_runtime.h>

typedef __fp16 half8_t __attribute__((ext_vector_type(8)));
typedef float  f4_t    __attribute__((ext_vector_type(4)));

__device__ __forceinline__ unsigned pk(float a, float b) {
    return __builtin_bit_cast(unsigned, __builtin_amdgcn_cvt_pkrtz(a, b));
}

// ---------------------------------------------------------------------------
// QKV fused: 1x1-conv via f16 MFMA (W f16 frag-order in LDS once per block,
// x converted inline). Grid 768 = 3 matrices x 256 groups; wave = 1 px-tile
// of 16, 32 MFMA. Output f16-packed [pos][c2]. Additionally, q-blocks
// precompute the relative-bias tables biasG[px][16] (j<7: bias_x[kj],
// 7..13: bias_y[ki]) from the per-px channel group-sums, which fall out of
// the D-fragments for free.
// ---------------------------------------------------------------------------
__global__ __launch_bounds__(256) void qkv_fused(
    const float* __restrict__ x, const float* __restrict__ wq,
    const float* __restrict__ wk, const float* __restrict__ wv,
    const float* __restrict__ relx, const float* __restrict__ rely,
    unsigned* __restrict__ qf, unsigned* __restrict__ kf,
    unsigned* __restrict__ vf, float* __restrict__ biasG)
{
    __shared__ __fp16 Af[2048 * 8];          // 32 KB A-frags
    __shared__ float  tl4[4][16 * 17];       // per-wave transpose buffer
    __shared__ float  sS[4][16 * 20];        // per-wave group sums [px][t]
    __shared__ float  relsQ[120];            // rel_x(56) ++ rel_y(56) ++ pad

    const int tid = threadIdx.x, wvn = tid >> 6, lane = tid & 63;
    const int mtx = blockIdx.x >> 8;         // 0=q 1=k 2=v
    const int tg  = blockIdx.x & 255;
    const float* wsrc = (mtx == 0) ? wq : (mtx == 1 ? wk : wv);
    unsigned*    dst  = (mtx == 0) ? qf : (mtx == 1 ? kf : vf);

    if (tid < 120)
        relsQ[tid] = (tid < 56) ? relx[tid] : (tid < 112 ? rely[tid - 56] : 0.f);

    // ---- stage W (128x128) as f16 A-frags ----
#pragma unroll
    for (int s = 0; s < 8; ++s) {
        const int it = s * 256 + tid;
        const int l = it & 63, ck = (it >> 6) & 3, ot = it >> 8;
        const float* wr = wsrc + (size_t)(ot * 16 + (l & 15)) * 128 + ck * 32 + (l >> 4) * 8;
        const float4 w0 = *(const float4*)wr;
        const float4 w1 = *(const float4*)(wr + 4);
        unsigned* d = (unsigned*)&Af[it * 8];
        d[0] = pk(w0.x, w0.y); d[1] = pk(w0.z, w0.w);
        d[2] = pk(w1.x, w1.y); d[3] = pk(w1.z, w1.w);
    }

    // ---- B-frags: this wave's 16-px x-tile ----
    const int t = tg * 4 + wvn;
    const int m = lane & 15, quad = lane >> 4;
    const int p0 = t * 16, b = p0 >> 12, hw = p0 & 4095;
    const float* xb = x + (size_t)b * (128 * 4096) + hw + m;
    half8_t B[4];
#pragma unroll
    for (int ck = 0; ck < 4; ++ck) {
        float f[8];
#pragma unroll
        for (int j = 0; j < 8; ++j) f[j] = xb[(size_t)(ck * 32 + quad * 8 + j) * 4096];
        unsigned* d = (unsigned*)&B[ck];
        d[0] = pk(f[0], f[1]); d[1] = pk(f[2], f[3]);
        d[2] = pk(f[4], f[5]); d[3] = pk(f[6], f[7]);
    }
    __syncthreads();

    float* tl = tl4[wvn];
    float s0 = 0.f, s1 = 0.f, s2 = 0.f, s3 = 0.f;   // group-sum partials
#pragma unroll
    for (int og = 0; og < 4; ++og) {
#pragma unroll
        for (int ot = 0; ot < 2; ++ot) {
            const int otile = og * 2 + ot;
            f4_t acc = {0.f, 0.f, 0.f, 0.f};
#pragma unroll
            for (int ck = 0; ck < 4; ++ck) {
                const half8_t A = *(const half8_t*)&Af[((otile * 4 + ck) * 64 + lane) * 8];
                acc = __builtin_amdgcn_mfma_f32_16x16x32_f16(A, B[ck], acc, 0, 0, 0);
            }
            if (mtx == 0) { s0 += acc[0]; s1 += acc[1]; s2 += acc[2]; s3 += acc[3]; }
            const int c2l = ot * 8 + quad * 2;
            tl[m * 17 + c2l]     = __builtin_bit_cast(float, pk(acc[0], acc[1]));
            tl[m * 17 + c2l + 1] = __builtin_bit_cast(float, pk(acc[2], acc[3]));
        }
        __asm__ volatile("s_waitcnt lgkmcnt(0)" ::: "memory");
        __builtin_amdgcn_wave_barrier();
#pragma unroll
        for (int s = 0; s < 4; ++s) {
            const int px = s * 4 + quad;
            dst[(size_t)(p0 + px) * 64 + og * 16 + m] =
                __builtin_bit_cast(unsigned, tl[px * 17 + m]);
        }
        __builtin_amdgcn_wave_barrier();
    }

    // ---- bias tables (q-blocks only): biasG[px][j] ----
    if (mtx == 0) {
        f4_t sv = {s0, s1, s2, s3};                     // t = quad*4 + e
        *(f4_t*)&sS[wvn][m * 20 + quad * 4] = sv;
        __asm__ volatile("s_waitcnt lgkmcnt(0)" ::: "memory");
        __builtin_amdgcn_wave_barrier();
        f4_t bj = {0.f, 0.f, 0.f, 0.f};
#pragma unroll
        for (int jj = 0; jj < 4; ++jj) {
            const int j = quad * 4 + jj;
            float s = 0.f;
            if (j < 7) {
#pragma unroll
                for (int tt = 0; tt < 8; ++tt)
                    s = fmaf(sS[wvn][m * 20 + tt], relsQ[tt * 7 + j], s);
            } else if (j < 14) {
#pragma unroll
                for (int tt = 0; tt < 8; ++tt)
                    s = fmaf(sS[wvn][m * 20 + 8 + tt], relsQ[56 + tt * 7 + (j - 7)], s);
            }
            bj[jj] = s;
        }
        *(f4_t*)(biasG + (size_t)(p0 + m) * 16 + quad * 4) = bj;
    }
}

// ---------------------------------------------------------------------------
// Attention, MFMA both phases. Block = 512 thr = 8 waves, producer/consumer:
//   waves 0-3: bias stage + QK^T (Q/K B-frags direct from global, OOB->0)
//              + softmax (D-layout) + weights -> aW   (16 px each, 2x8 rows)
//   waves 4-7: concurrently stage V^T halo into vH (register v_perm
//              transpose) + zero tail — previously this serialized in front
//              of QK behind a block barrier, at 1 wave/SIMD occupancy.
// One __syncthreads, then PV split across ALL 8 waves: wave w handles the
// px-tile of source wave (w&3) and channel tiles tn = (w>>2)*4 .. +3.
// => 2 waves/SIMD occupancy + stage/compute overlap. LDS unchanged (77 KB).
// ---------------------------------------------------------------------------
__global__ __launch_bounds__(512) void attn_mfma(
    const unsigned* __restrict__ qf, const unsigned* __restrict__ kf,
    const unsigned* __restrict__ vf, const float* __restrict__ biasG,
    float* __restrict__ out)
{
    __shared__ __fp16 vH[128 * 216];         // 55,296 B  [c][halo pos 196+pad]
    __shared__ __fp16 aW[4 * 16 * 136];      // 17,408 B  per-src-wave weights
    __shared__ float  biasL[64 * 17];        //  4,352 B

    const int tid = threadIdx.x, bx = blockIdx.x;
    const int wv = tid >> 6, lane = tid & 63;
    const int n = lane & 15, quad = lane >> 4;
    const int w0 = (bx & 7) * 8, h0 = ((bx >> 3) & 7) * 8, b = bx >> 6;

    if (wv >= 4) {
        // ================= producer waves: stage V^T halo =================
        const int st = tid & 255;
        for (int i = st; i < 1568; i += 256) {
            const int pq = i >> 5, c2p = i & 31;
            const int pos0 = pq * 4;
            unsigned dx[4], dy[4];
#pragma unroll
            for (int p = 0; p < 4; ++p) {
                const int pos = pos0 + p;
                const int ri = (pos * 2341) >> 15;          // pos/14, pos<196
                const int ci = pos - ri * 14;
                const int py = h0 - 3 + ri, px = w0 - 3 + ci;
                uint2 d = make_uint2(0u, 0u);
                if ((unsigned)py < 64u && (unsigned)px < 64u)
                    d = *(const uint2*)(vf + (size_t)((b * 4096 + py * 64 + px) * 64 + c2p * 2));
                dx[p] = d.x; dy[p] = d.y;
            }
            const int c0 = c2p * 4;
            *(uint2*)(vH + (c0 + 0) * 216 + pos0) = make_uint2(
                __builtin_amdgcn_perm(dx[1], dx[0], 0x05040100u),
                __builtin_amdgcn_perm(dx[3], dx[2], 0x05040100u));
            *(uint2*)(vH + (c0 + 1) * 216 + pos0) = make_uint2(
                __builtin_amdgcn_perm(dx[1], dx[0], 0x07060302u),
                __builtin_amdgcn_perm(dx[3], dx[2], 0x07060302u));
            *(uint2*)(vH + (c0 + 2) * 216 + pos0) = make_uint2(
                __builtin_amdgcn_perm(dy[1], dy[0], 0x05040100u),
                __builtin_amdgcn_perm(dy[3], dy[2], 0x05040100u));
            *(uint2*)(vH + (c0 + 3) * 216 + pos0) = make_uint2(
                __builtin_amdgcn_perm(dy[1], dy[0], 0x07060302u),
                __builtin_amdgcn_perm(dy[3], dy[2], 0x07060302u));
        }
        // zero pad tail pos 196..215 (128 rows x 5 uint2)
        for (int i = st; i < 640; i += 256) {
            const int c = i / 5, s = i - c * 5;
            *(uint2*)(vH + c * 216 + 196 + s * 4) = make_uint2(0u, 0u);
        }
    } else {
        // ================= consumer waves: QK^T + softmax =================
        // bias tables for this wave's 16 px
        for (int i = lane; i < 256; i += 64) {
            const int pxl = i >> 4, tt = i & 15;
            const int px = wv * 16 + pxl;
            const int pix = b * 4096 + (h0 + (px >> 3)) * 64 + w0 + (px & 7);
            biasL[px * 17 + tt] = biasG[(size_t)pix * 16 + tt];
        }
        __asm__ volatile("s_waitcnt lgkmcnt(0)" ::: "memory");
        __builtin_amdgcn_wave_barrier();

        const int wrow = h0 + wv * 2;
        uint4 qA[4];
#pragma unroll
        for (int kc = 0; kc < 4; ++kc) {
            const int pix = b * 4096 + (wrow + (n >> 3)) * 64 + w0 + (n & 7);
            qA[kc] = *(const uint4*)(qf + (size_t)pix * 64 + kc * 16 + quad * 4);
        }
        f4_t lg[7];
#pragma unroll
        for (int t = 0; t < 7; ++t) {
            const int posL = t * 16 + n;                     // 0..111
            const int ri = (posL * 2341) >> 15;
            const int ci = posL - ri * 14;
            const int py = wrow - 3 + ri, pxc = w0 - 3 + ci;
            const bool val = ((unsigned)py < 64u) && ((unsigned)pxc < 64u);
            const int pix = b * 4096 + py * 64 + pxc;
            f4_t acc = {0.f, 0.f, 0.f, 0.f};
#pragma unroll
            for (int kc = 0; kc < 4; ++kc) {
                uint4 kB = make_uint4(0u, 0u, 0u, 0u);
                if (val) kB = *(const uint4*)(kf + (size_t)pix * 64 + kc * 16 + quad * 4);
                acc = __builtin_amdgcn_mfma_f32_16x16x32_f16(
                    __builtin_bit_cast(half8_t, qA[kc]),
                    __builtin_bit_cast(half8_t, kB), acc, 0, 0, 0);
            }
            lg[t] = acc;
        }

        // ---- mask + bias + per-px softmax (D-layout), weights -> aW ----
        const int pad = (wv & 1) * 4;                        // 16B-align shift
        {   // zero aW head/tail chunks (4 uint2 per px row)
            const int row = lane >> 2, ch = lane & 3;
            const int off = pad ? (ch == 0 ? 0 : 112 + pad + (ch - 1) * 4)
                                : 112 + ch * 4;
            *(uint2*)(aW + wv * 2176 + row * 136 + off) = make_uint2(0u, 0u);
        }
#pragma unroll
        for (int i = 0; i < 4; ++i) {
            const int px = quad * 4 + i;                     // wave-local px id
            const int dr = px >> 3, dw = px & 7;
            const float* bb = &biasL[(wv * 16 + px) * 17];
            float mx = -1e30f;
#pragma unroll
            for (int t = 0; t < 7; ++t) {
                const int posL = t * 16 + n;
                const int ri = (posL * 2341) >> 15;
                const int ci = posL - ri * 14;
                const unsigned ki = ri - dr, kj = ci - dw;
                float v = -1e30f;
                if (ki < 7u && kj < 7u) v = lg[t][i] + bb[kj] + bb[7 + ki];
                lg[t][i] = v;
                mx = fmaxf(mx, v);
            }
            mx = fmaxf(mx, __shfl_xor(mx, 1));
            mx = fmaxf(mx, __shfl_xor(mx, 2));
            mx = fmaxf(mx, __shfl_xor(mx, 4));
            mx = fmaxf(mx, __shfl_xor(mx, 8));
            float ss = 0.f;
#pragma unroll
            for (int t = 0; t < 7; ++t) {
                const float e = __expf(lg[t][i] - mx);
                lg[t][i] = e;
                ss += e;
            }
            ss += __shfl_xor(ss, 1);
            ss += __shfl_xor(ss, 2);
            ss += __shfl_xor(ss, 4);
            ss += __shfl_xor(ss, 8);
            const float inv = 1.f / ss;
#pragma unroll
            for (int t = 0; t < 7; ++t)
                aW[wv * 2176 + px * 136 + pad + t * 16 + n] = (__fp16)(lg[t][i] * inv);
        }
    }

    __syncthreads();   // vH (waves 4-7) + aW (waves 0-3) both complete

    // ---- Phase B: PV via MFMA, all 8 waves; wave w = src tile (w&3),
    //      channel tiles tn = (w>>2)*4 .. +3; fp32 D stored direct ----
    const int wvS = wv & 3;
    const int padS = (wvS & 1) * 4;
    const int startw = wvS * 28 - padS;                  // {0,24,56,80}
    const int wrowS = h0 + wvS * 2;
    const int tnB = (wv >> 2) * 4;
    uint4 pA[4];
#pragma unroll
    for (int kc = 0; kc < 4; ++kc)
        pA[kc] = *(const uint4*)(aW + wvS * 2176 + n * 136 + kc * 32 + quad * 8);
#pragma unroll
    for (int tt = 0; tt < 4; ++tt) {
        const int tn = tnB + tt;
        f4_t acc = {0.f, 0.f, 0.f, 0.f};
#pragma unroll
        for (int kc = 0; kc < 4; ++kc) {
            const half8_t vB = *(const half8_t*)(vH + (tn * 16 + n) * 216 +
                                                 startw + kc * 32 + quad * 8);
            acc = __builtin_amdgcn_mfma_f32_16x16x32_f16(
                __builtin_bit_cast(half8_t, pA[kc]), vB, acc, 0, 0, 0);
        }
        const int c = tn * 16 + n;
#pragma unroll
        for (int i = 0; i < 4; ++i) {
            const int px = quad * 4 + i;
            const int hwp = (wrowS + (px >> 3)) * 64 + w0 + (px & 7);
            out[(size_t)(b * 128 + c) * 4096 + hwp] = acc[i];
        }
    }
}

extern "C" void kernel_launch(void* const* d_in, const int* in_sizes, int n_in,
                              void* d_out, int out_size, void* d_ws, size_t ws_size,
                              hipStream_t stream) {
    const float* x    = (const float*)d_in[0];
    const float* wq   = (const float*)d_in[1];
    const float* wk   = (const float*)d_in[2];
    const float* wv   = (const float*)d_in[3];
    const float* relx = (const float*)d_in[4];
    const float* rely = (const float*)d_in[5];
    float* out = (float*)d_out;

    char* ws = (char*)d_ws;
    unsigned* qfb = (unsigned*)(ws);                 // 4 MB f16-packed [pos][c2]
    unsigned* kfb = (unsigned*)(ws + 0x400000);      // 4 MB
    unsigned* vfb = (unsigned*)(ws + 0x800000);      // 4 MB
    float*    bG  = (float*)   (ws + 0xC00000);      // 1 MB bias tables

    qkv_fused<<<dim3(768), 256, 0, stream>>>(x, wq, wk, wv, relx, rely,
                                             qfb, kfb, vfb, bG);
    attn_mfma<<<dim3(256), 512, 0, stream>>>(qfb, kfb, vfb, bG, out);
}